// Round 2
// baseline (168.513 us; speedup 1.0000x reference)
//
#include <hip/hip_runtime.h>
#include <hip/hip_bf16.h>
#include <stdint.h>

// Problem constants: B=2, L=2048, D=1024, H=16, hd=64, scale=1/8 (log2e-folded).

typedef __bf16 bf16x8 __attribute__((ext_vector_type(8)));
typedef __bf16 bf16x4v __attribute__((ext_vector_type(4)));
typedef float f32x4 __attribute__((ext_vector_type(4)));

__device__ __forceinline__ unsigned short f2bf(float f) {
  union { float f; unsigned int u; } v; v.f = f;
  unsigned int r = v.u + 0x7FFFu + ((v.u >> 16) & 1u);  // RNE
  return (unsigned short)(r >> 16);
}
__device__ __forceinline__ float b2f(unsigned short u) {
  union { unsigned int u; float f; } v; v.u = ((unsigned int)u) << 16;
  return v.f;
}

__device__ __forceinline__ void gl2lds16(const void* gptr, void* lptr) {
  __builtin_amdgcn_global_load_lds(
      (const __attribute__((address_space(1))) unsigned int*)gptr,
      (__attribute__((address_space(3))) unsigned int*)lptr, 16, 0, 0);
}

// ---------------- fp32 -> bf16 conversion (fused: x | W_qkv | W_out) --------
// Destinations are contiguous in ws: xb (8MB) | wqb (6MB) | wob (2MB).
__global__ void cvt_all(const float4* __restrict__ x,
                        const float4* __restrict__ wq,
                        const float4* __restrict__ wo,
                        ushort4* __restrict__ dst) {
  int i = blockIdx.x * 256 + threadIdx.x;  // 0..2097151
  float4 v;
  if (i < 1048576) v = x[i];
  else if (i < 1835008) v = wq[i - 1048576];
  else v = wo[i - 1835008];
  ushort4 o;
  o.x = f2bf(v.x); o.y = f2bf(v.y); o.z = f2bf(v.z); o.w = f2bf(v.w);
  dst[i] = o;
}

// ---------------- GEMM: C[M,N] = A[M,K] * B[N,K]^T (both K-contiguous) ------
// m97-style: 128x128 tile, BK=32, 4 waves (2x2), global_load_lds width 16.
template<int OUT_BF16>
__global__ __launch_bounds__(256) void gemm_bt(
    const __hip_bfloat16* __restrict__ A,
    const __hip_bfloat16* __restrict__ B,
    void* __restrict__ C, int M, int N, int K) {
  __shared__ __align__(16) __hip_bfloat16 As[128 * 32];
  __shared__ __align__(16) __hip_bfloat16 Bs[128 * 32];
  const int tid = threadIdx.x;
  const int lane = tid & 63;
  const int wave = tid >> 6;
  const int wm = (wave >> 1) * 64, wn = (wave & 1) * 64;
  const int g = lane >> 4, lr = lane & 15;
  const int m0 = blockIdx.y * 128, n0 = blockIdx.x * 128;
  f32x4 acc[4][4] = {};

  const char* Ag = (const char*)(A + (size_t)m0 * K);
  const char* Bg = (const char*)(B + (size_t)n0 * K);
  const size_t ldb = (size_t)K * 2;  // row stride bytes

  for (int kt = 0; kt < K; kt += 32) {
    const char* Ak = Ag + (size_t)kt * 2;
    const char* Bk = Bg + (size_t)kt * 2;
#pragma unroll
    for (int j = 0; j < 2; ++j) {
      int c = tid + j * 256;           // 16B chunk index, 0..511
      int row = c >> 2;                // 4 chunks per 64B row
      int colb = (c & 3) * 16;
      gl2lds16(Ak + (size_t)row * ldb + colb, (char*)As + c * 16);
      gl2lds16(Bk + (size_t)row * ldb + colb, (char*)Bs + c * 16);
    }
    asm volatile("s_waitcnt vmcnt(0)" ::: "memory");
    __syncthreads();
    bf16x8 af[4], bfr[4];
#pragma unroll
    for (int i = 0; i < 4; ++i)
      af[i] = *(const bf16x8*)((const char*)As + (size_t)(wm + i * 16 + lr) * 64 + g * 16);
#pragma unroll
    for (int i = 0; i < 4; ++i)
      bfr[i] = *(const bf16x8*)((const char*)Bs + (size_t)(wn + i * 16 + lr) * 64 + g * 16);
#pragma unroll
    for (int i = 0; i < 4; ++i)
#pragma unroll
      for (int j = 0; j < 4; ++j)
        acc[i][j] = __builtin_amdgcn_mfma_f32_16x16x32_bf16(af[i], bfr[j], acc[i][j], 0, 0, 0);
    __syncthreads();
  }

  // Epilogue. C/D layout: n = lane&15 (+16*nf), m = 4*(lane>>4)+reg (+16*mf).
#pragma unroll
  for (int i = 0; i < 4; ++i) {
#pragma unroll
    for (int j = 0; j < 4; ++j) {
      int n = n0 + wn + j * 16 + lr;
#pragma unroll
      for (int r = 0; r < 4; ++r) {
        int m = m0 + wm + i * 16 + g * 4 + r;
        float v = acc[i][j][r];
        if (OUT_BF16) {
          ((unsigned short*)C)[(size_t)m * N + n] = f2bf(v);
        } else {
          ((float*)C)[(size_t)m * N + n] = v;
        }
      }
    }
  }
}

// ---------------- RoPE + scatter to per-head Q,K,V(transposed) ----------------
// qkv: bf16 [B*L][3*1024]. Writes:
//   Qs[bh][l][64] (scaled by log2e/8 so softmax uses exp2), Ks[bh][l][64], Vt[bh][64][L].
__global__ void rope_scatter(const __hip_bfloat16* __restrict__ qkv,
                             __hip_bfloat16* __restrict__ Qs,
                             __hip_bfloat16* __restrict__ Ks,
                             __hip_bfloat16* __restrict__ Vt) {
  const int t = blockIdx.x * 256 + threadIdx.x;  // 262144 total
  const int i = t & 31;          // rope pair index 0..31
  const int lc = (t >> 5) & 255; // chunk of 8 positions
  const int h = (t >> 13) & 15;
  const int b = t >> 17;
  const float inv_freq = powf(10000.0f, -(float)i * (1.0f / 32.0f));
  const float QSCALE = 0.125f * 1.44269504088896f;  // scale * log2(e)
  const unsigned short* qk = (const unsigned short*)qkv;
  unsigned short v0[8], v1[8];
#pragma unroll
  for (int j = 0; j < 8; ++j) {
    const int l = lc * 8 + j;
    const size_t row = ((size_t)(b * 2048 + l)) * 3072;
    float s, c;
    sincosf((float)l * inv_freq, &s, &c);
    ushort2 qp = *(const ushort2*)(qk + row + h * 64 + 2 * i);
    ushort2 kp = *(const ushort2*)(qk + row + 1024 + h * 64 + 2 * i);
    ushort2 vp = *(const ushort2*)(qk + row + 2048 + h * 64 + 2 * i);
    float x1 = b2f(qp.x), x2 = b2f(qp.y);
    float y1 = b2f(kp.x), y2 = b2f(kp.y);
    size_t oidx = (((size_t)(b * 16 + h)) * 2048 + l) * 64 + 2 * i;
    ushort2 qo, ko;
    qo.x = f2bf((x1 * c - x2 * s) * QSCALE);
    qo.y = f2bf((x1 * s + x2 * c) * QSCALE);
    ko.x = f2bf(y1 * c - y2 * s);
    ko.y = f2bf(y1 * s + y2 * c);
    *(ushort2*)((unsigned short*)Qs + oidx) = qo;
    *(ushort2*)((unsigned short*)Ks + oidx) = ko;
    v0[j] = vp.x; v1[j] = vp.y;
  }
  unsigned short* Vtu = (unsigned short*)Vt;
  const size_t vrow0 = (((size_t)(b * 16 + h)) * 64 + 2 * i) * 2048 + lc * 8;
  const size_t vrow1 = vrow0 + 2048;
  *(ushort4*)(Vtu + vrow0)     = make_ushort4(v0[0], v0[1], v0[2], v0[3]);
  *(ushort4*)(Vtu + vrow0 + 4) = make_ushort4(v0[4], v0[5], v0[6], v0[7]);
  *(ushort4*)(Vtu + vrow1)     = make_ushort4(v1[0], v1[1], v1[2], v1[3]);
  *(ushort4*)(Vtu + vrow1 + 4) = make_ushort4(v1[4], v1[5], v1[6], v1[7]);
}

// ---------------- Flash attention ----------------
// Grid: 1024 blocks = (bh) x (qtile). XCD-swizzled so one bh's 32 q-tile
// blocks share one XCD's L2 (K+V per bh = 512KB << 4MB).
// 4 waves, 16 q-rows each. Swapped QK^T: S^T = mfma(A=K, B=Q) so each lane
// owns P values of one q-row. K/Vt tiles double-buffered with counted vmcnt
// + raw s_barrier (T3/T4-lite); XOR-swizzled on both sides (rule 21).
// Softmax in exp2 units (log2e folded into Q); defer-max rescale (T13).
__global__ __launch_bounds__(256) void attn_fwd(
    const __hip_bfloat16* __restrict__ Qs,
    const __hip_bfloat16* __restrict__ Ks,
    const __hip_bfloat16* __restrict__ Vt,
    __hip_bfloat16* __restrict__ Ob) {
  constexpr int L = 2048;
  constexpr int NT = L / 64;
  __shared__ __align__(16) __hip_bfloat16 Kt[2][64 * 64];
  __shared__ __align__(16) __hip_bfloat16 Vts[2][64 * 64];
  __shared__ __align__(16) __hip_bfloat16 Pw[4][16][72];  // padded rows (144B)
  const int tid = threadIdx.x, lane = tid & 63, w = tid >> 6;
  const int g = lane >> 4, lr = lane & 15;
  // XCD swizzle: dispatch maps blockIdx%8 -> XCD; give each XCD 4 whole bh.
  const int blk = blockIdx.x;
  const int slot = blk >> 3;
  const int bh = (blk & 7) * 4 + (slot >> 5);
  const int qt = slot & 31;
  const int q = qt * 64 + w * 16 + lr;

  const __hip_bfloat16* Qrow = Qs + ((size_t)bh * L + q) * 64;
  bf16x8 qf[2];
  qf[0] = *(const bf16x8*)(Qrow + g * 8);
  qf[1] = *(const bf16x8*)(Qrow + 32 + g * 8);

  f32x4 oacc[4] = {};
  float mrun = -1e30f, lpart = 0.0f;
  const char* Kbase = (const char*)(Ks + (size_t)bh * L * 64);
  const char* Vbase = (const char*)(Vt + (size_t)bh * 64 * L);

  auto stage = [&](int buf, int kt) {
#pragma unroll
    for (int j = 0; j < 2; ++j) {
      int c = tid + j * 256;
      int o = c * 16;
      int os = o ^ (((o >> 7) & 7) << 4);  // involution
      gl2lds16(Kbase + (size_t)kt * 8192 + os, (char*)Kt[buf] + o);
      int vrow = os >> 7, vcol = os & 127;
      gl2lds16(Vbase + (size_t)vrow * (L * 2) + kt * 128 + vcol, (char*)Vts[buf] + o);
    }
  };

  stage(0, 0);  // 4 loads/thread in flight

  for (int kt = 0; kt < NT; ++kt) {
    const int cur = kt & 1;
    if (kt + 1 < NT) {
      stage(cur ^ 1, kt + 1);
      asm volatile("s_waitcnt vmcnt(4)" ::: "memory");  // cur's 4 loads done
    } else {
      asm volatile("s_waitcnt vmcnt(0)" ::: "memory");
    }
    __builtin_amdgcn_s_barrier();  // cur tile visible to all waves

    const char* Kc = (const char*)Kt[cur];
    const char* Vc = (const char*)Vts[cur];

    // QK^T (swapped): sacc[mf] holds S^T[k-rows mf*16+4g+r][q=lr], log2 units
    f32x4 sacc[4] = {};
#pragma unroll
    for (int mf = 0; mf < 4; ++mf) {
      int row = mf * 16 + lr;
#pragma unroll
      for (int ds = 0; ds < 2; ++ds) {
        int addr = (row * 128 + ds * 64 + g * 16) ^ ((row & 7) << 4);
        bf16x8 a = *(const bf16x8*)(Kc + addr);
        sacc[mf] = __builtin_amdgcn_mfma_f32_16x16x32_bf16(a, qf[ds], sacc[mf], 0, 0, 0);
      }
    }

    // Online softmax in log2 units; defer-max: skip O-rescale if growth <= 8.
    float t0 = fmaxf(fmaxf(sacc[0][0], sacc[0][1]), fmaxf(sacc[0][2], sacc[0][3]));
    float t1 = fmaxf(fmaxf(sacc[1][0], sacc[1][1]), fmaxf(sacc[1][2], sacc[1][3]));
    float t2 = fmaxf(fmaxf(sacc[2][0], sacc[2][1]), fmaxf(sacc[2][2], sacc[2][3]));
    float t3 = fmaxf(fmaxf(sacc[3][0], sacc[3][1]), fmaxf(sacc[3][2], sacc[3][3]));
    float tmax = fmaxf(fmaxf(t0, t1), fmaxf(t2, t3));
    tmax = fmaxf(tmax, __shfl_xor(tmax, 16));
    tmax = fmaxf(tmax, __shfl_xor(tmax, 32));
    if (__any(tmax > mrun + 8.0f)) {
      float mnew = fmaxf(mrun, tmax);
      float alpha = __builtin_amdgcn_exp2f(mrun - mnew);
      mrun = mnew;
      lpart *= alpha;
#pragma unroll
      for (int d = 0; d < 4; ++d) oacc[d] = oacc[d] * alpha;
    }
#pragma unroll
    for (int mf = 0; mf < 4; ++mf) {
      float p0 = __builtin_amdgcn_exp2f(sacc[mf][0] - mrun);
      float p1 = __builtin_amdgcn_exp2f(sacc[mf][1] - mrun);
      float p2 = __builtin_amdgcn_exp2f(sacc[mf][2] - mrun);
      float p3 = __builtin_amdgcn_exp2f(sacc[mf][3] - mrun);
      lpart += (p0 + p1) + (p2 + p3);
      bf16x4v pk = { (__bf16)p0, (__bf16)p1, (__bf16)p2, (__bf16)p3 };
      *(bf16x4v*)((char*)(&Pw[w][lr][0]) + mf * 32 + g * 8) = pk;
    }
    asm volatile("s_waitcnt lgkmcnt(0)" ::: "memory");
    __builtin_amdgcn_sched_barrier(0);

    // PV: O^T = mfma(A=Vt, B=P); oacc[df] holds O^T[d=df*16+4g+r][q=lr]
#pragma unroll
    for (int ks = 0; ks < 2; ++ks) {
      bf16x8 pfrag = *(const bf16x8*)((const char*)(&Pw[w][lr][0]) + ks * 64 + g * 16);
#pragma unroll
      for (int df = 0; df < 4; ++df) {
        int row = df * 16 + lr;
        int addr = (row * 128 + ks * 64 + g * 16) ^ ((row & 7) << 4);
        bf16x8 a = *(const bf16x8*)(Vc + addr);
        oacc[df] = __builtin_amdgcn_mfma_f32_16x16x32_bf16(a, pfrag, oacc[df], 0, 0, 0);
      }
    }
    __builtin_amdgcn_s_barrier();  // all waves done reading cur before overwrite
  }

  float lsum = lpart;
  lsum += __shfl_xor(lsum, 16);
  lsum += __shfl_xor(lsum, 32);
  float inv = 1.0f / lsum;

  const int b = bh >> 4, h = bh & 15;
  unsigned short* orow = (unsigned short*)Ob + ((size_t)(b * L + q)) * 1024 + h * 64;
#pragma unroll
  for (int df = 0; df < 4; ++df) {
    ushort4 o4;
    o4.x = f2bf(oacc[df][0] * inv);
    o4.y = f2bf(oacc[df][1] * inv);
    o4.z = f2bf(oacc[df][2] * inv);
    o4.w = f2bf(oacc[df][3] * inv);
    *(ushort4*)(orow + df * 16 + g * 4) = o4;
  }
}

// ---------------- launch ----------------
extern "C" void kernel_launch(void* const* d_in, const int* in_sizes, int n_in,
                              void* d_out, int out_size, void* d_ws, size_t ws_size,
                              hipStream_t stream) {
  (void)in_sizes; (void)n_in; (void)out_size; (void)ws_size;
  const float* x    = (const float*)d_in[0];   // [2,2048,1024]
  const float* wqkv = (const float*)d_in[1];   // [3072,1024]
  const float* wout = (const float*)d_in[2];   // [1024,1024]

  char* ws = (char*)d_ws;
  // Workspace layout (needs 64 MB):
  auto* xb   = (__hip_bfloat16*)(ws + (size_t)(0u));          // 8 MB
  auto* wqb  = (__hip_bfloat16*)(ws + ((size_t)8u << 20));    // 6 MB
  auto* wob  = (__hip_bfloat16*)(ws + ((size_t)14u << 20));   // 2 MB
  auto* qkvb = (__hip_bfloat16*)(ws + ((size_t)16u << 20));   // 24 MB [4096][3072]
  auto* Ob   = (__hip_bfloat16*)(ws + ((size_t)16u << 20));   // 8 MB, overlaps dead qkvb
  auto* Qsb  = (__hip_bfloat16*)(ws + ((size_t)40u << 20));   // 8 MB [32][2048][64]
  auto* Ksb  = (__hip_bfloat16*)(ws + ((size_t)48u << 20));   // 8 MB
  auto* Vtb  = (__hip_bfloat16*)(ws + ((size_t)56u << 20));   // 8 MB [32][64][2048]

  cvt_all<<<8192, 256, 0, stream>>>((const float4*)x, (const float4*)wqkv,
                                    (const float4*)wout, (ushort4*)xb);

  gemm_bt<1><<<dim3(24, 32), 256, 0, stream>>>(xb, wqb, (void*)qkvb, 4096, 3072, 1024);
  rope_scatter<<<1024, 256, 0, stream>>>(qkvb, Qsb, Ksb, Vtb);
  attn_fwd<<<1024, 256, 0, stream>>>(Qsb, Ksb, Vtb, Ob);
  gemm_bt<0><<<dim3(8, 32), 256, 0, stream>>>(Ob, wob, d_out, 4096, 1024, 1024);
}

// Round 3
// 160.990 us; speedup vs baseline: 1.0467x; 1.0467x over previous
//
#include <hip/hip_runtime.h>
#include <hip/hip_bf16.h>
#include <stdint.h>

// Problem constants: B=2, L=2048, D=1024, H=16, hd=64, scale=1/8 (log2e-folded).

typedef __bf16 bf16x8 __attribute__((ext_vector_type(8)));
typedef __bf16 bf16x4v __attribute__((ext_vector_type(4)));
typedef float f32x4 __attribute__((ext_vector_type(4)));

__device__ __forceinline__ unsigned short f2bf(float f) {
  union { float f; unsigned int u; } v; v.f = f;
  unsigned int r = v.u + 0x7FFFu + ((v.u >> 16) & 1u);  // RNE
  return (unsigned short)(r >> 16);
}
__device__ __forceinline__ float b2f(unsigned short u) {
  union { unsigned int u; float f; } v; v.u = ((unsigned int)u) << 16;
  return v.f;
}

__device__ __forceinline__ void gl2lds16(const void* gptr, void* lptr) {
  __builtin_amdgcn_global_load_lds(
      (const __attribute__((address_space(1))) unsigned int*)gptr,
      (__attribute__((address_space(3))) unsigned int*)lptr, 16, 0, 0);
}

// ---------------- fp32 -> bf16 conversion (x | W_qkv | W_out) ----------------
__global__ void cvt_all(const float4* __restrict__ x,
                        const float4* __restrict__ wq,
                        const float4* __restrict__ wo,
                        ushort4* __restrict__ xb,
                        ushort4* __restrict__ wqb,
                        ushort4* __restrict__ wob) {
  int i = blockIdx.x * 256 + threadIdx.x;  // 0..2097151
  float4 v; ushort4* dst; int j;
  if (i < 1048576)      { v = x[i];            dst = xb;  j = i; }
  else if (i < 1835008) { v = wq[i - 1048576]; dst = wqb; j = i - 1048576; }
  else                  { v = wo[i - 1835008]; dst = wob; j = i - 1835008; }
  ushort4 o;
  o.x = f2bf(v.x); o.y = f2bf(v.y); o.z = f2bf(v.z); o.w = f2bf(v.w);
  dst[j] = o;
}

// ---------------- GEMM: C[M,N] = A[M,K] * B[N,K]^T (both K-contiguous) ------
template<int OUT_BF16>
__global__ __launch_bounds__(256) void gemm_bt(
    const __hip_bfloat16* __restrict__ A,
    const __hip_bfloat16* __restrict__ B,
    void* __restrict__ C, int M, int N, int K) {
  __shared__ __align__(16) __hip_bfloat16 As[128 * 32];
  __shared__ __align__(16) __hip_bfloat16 Bs[128 * 32];
  const int tid = threadIdx.x;
  const int lane = tid & 63;
  const int wave = tid >> 6;
  const int wm = (wave >> 1) * 64, wn = (wave & 1) * 64;
  const int g = lane >> 4, lr = lane & 15;
  const int m0 = blockIdx.y * 128, n0 = blockIdx.x * 128;
  f32x4 acc[4][4] = {};

  const char* Ag = (const char*)(A + (size_t)m0 * K);
  const char* Bg = (const char*)(B + (size_t)n0 * K);
  const size_t ldb = (size_t)K * 2;

  for (int kt = 0; kt < K; kt += 32) {
    const char* Ak = Ag + (size_t)kt * 2;
    const char* Bk = Bg + (size_t)kt * 2;
#pragma unroll
    for (int j = 0; j < 2; ++j) {
      int c = tid + j * 256;
      int row = c >> 2;
      int colb = (c & 3) * 16;
      gl2lds16(Ak + (size_t)row * ldb + colb, (char*)As + c * 16);
      gl2lds16(Bk + (size_t)row * ldb + colb, (char*)Bs + c * 16);
    }
    asm volatile("s_waitcnt vmcnt(0)" ::: "memory");
    __syncthreads();
    bf16x8 af[4], bfr[4];
#pragma unroll
    for (int i = 0; i < 4; ++i)
      af[i] = *(const bf16x8*)((const char*)As + (size_t)(wm + i * 16 + lr) * 64 + g * 16);
#pragma unroll
    for (int i = 0; i < 4; ++i)
      bfr[i] = *(const bf16x8*)((const char*)Bs + (size_t)(wn + i * 16 + lr) * 64 + g * 16);
#pragma unroll
    for (int i = 0; i < 4; ++i)
#pragma unroll
      for (int j = 0; j < 4; ++j)
        acc[i][j] = __builtin_amdgcn_mfma_f32_16x16x32_bf16(af[i], bfr[j], acc[i][j], 0, 0, 0);
    __syncthreads();
  }

#pragma unroll
  for (int i = 0; i < 4; ++i) {
#pragma unroll
    for (int j = 0; j < 4; ++j) {
      int n = n0 + wn + j * 16 + lr;
#pragma unroll
      for (int r = 0; r < 4; ++r) {
        int m = m0 + wm + i * 16 + g * 4 + r;
        float v = acc[i][j][r];
        if (OUT_BF16) {
          ((unsigned short*)C)[(size_t)m * N + n] = f2bf(v);
        } else {
          ((float*)C)[(size_t)m * N + n] = v;
        }
      }
    }
  }
}

// ---------------- RoPE + scatter to per-head Q,K,V(transposed) --------------
__global__ void rope_scatter(const __hip_bfloat16* __restrict__ qkv,
                             __hip_bfloat16* __restrict__ Qs,
                             __hip_bfloat16* __restrict__ Ks,
                             __hip_bfloat16* __restrict__ Vt) {
  const int t = blockIdx.x * 256 + threadIdx.x;  // 262144 total
  const int i = t & 31;
  const int lc = (t >> 5) & 255;
  const int h = (t >> 13) & 15;
  const int b = t >> 17;
  const float inv_freq = powf(10000.0f, -(float)i * (1.0f / 32.0f));
  const float QSCALE = 0.125f * 1.44269504088896f;  // scale * log2(e)
  const unsigned short* qk = (const unsigned short*)qkv;
  unsigned short v0[8], v1[8];
#pragma unroll
  for (int j = 0; j < 8; ++j) {
    const int l = lc * 8 + j;
    const size_t row = ((size_t)(b * 2048 + l)) * 3072;
    float s, c;
    sincosf((float)l * inv_freq, &s, &c);
    ushort2 qp = *(const ushort2*)(qk + row + h * 64 + 2 * i);
    ushort2 kp = *(const ushort2*)(qk + row + 1024 + h * 64 + 2 * i);
    ushort2 vp = *(const ushort2*)(qk + row + 2048 + h * 64 + 2 * i);
    float x1 = b2f(qp.x), x2 = b2f(qp.y);
    float y1 = b2f(kp.x), y2 = b2f(kp.y);
    size_t oidx = (((size_t)(b * 16 + h)) * 2048 + l) * 64 + 2 * i;
    ushort2 qo, ko;
    qo.x = f2bf((x1 * c - x2 * s) * QSCALE);
    qo.y = f2bf((x1 * s + x2 * c) * QSCALE);
    ko.x = f2bf(y1 * c - y2 * s);
    ko.y = f2bf(y1 * s + y2 * c);
    *(ushort2*)((unsigned short*)Qs + oidx) = qo;
    *(ushort2*)((unsigned short*)Ks + oidx) = ko;
    v0[j] = vp.x; v1[j] = vp.y;
  }
  unsigned short* Vtu = (unsigned short*)Vt;
  const size_t vrow0 = (((size_t)(b * 16 + h)) * 64 + 2 * i) * 2048 + lc * 8;
  const size_t vrow1 = vrow0 + 2048;
  *(ushort4*)(Vtu + vrow0)     = make_ushort4(v0[0], v0[1], v0[2], v0[3]);
  *(ushort4*)(Vtu + vrow0 + 4) = make_ushort4(v0[4], v0[5], v0[6], v0[7]);
  *(ushort4*)(Vtu + vrow1)     = make_ushort4(v1[0], v1[1], v1[2], v1[3]);
  *(ushort4*)(Vtu + vrow1 + 4) = make_ushort4(v1[4], v1[5], v1[6], v1[7]);
}

// ---------------- Flash attention, split-K=2, partial outputs ----------------
// Grid: 2048 blocks = (bh 0..31) x (qtile 0..31) x (half 0..1), XCD-swizzled.
// 4 waves x 16 q-rows. Single-buffered K/V (16.4KB LDS); P aliases the Kt
// tile (dead after QK^T) with a mid-iteration barrier. Swapped QK^T; softmax
// in exp2 units; defer-max. Writes unnormalized O-partials (f32) + (m,l).
__global__ __launch_bounds__(256, 7) void attn_fwd(
    const __hip_bfloat16* __restrict__ Qs,
    const __hip_bfloat16* __restrict__ Ks,
    const __hip_bfloat16* __restrict__ Vt,
    float* __restrict__ Opart,
    float2* __restrict__ Ml) {
  constexpr int L = 2048;
  __shared__ __align__(16) __hip_bfloat16 Kt[64 * 64];   // reused as P after QK
  __shared__ __align__(16) __hip_bfloat16 Vts[64 * 64];
  const int tid = threadIdx.x, lane = tid & 63, w = tid >> 6;
  const int g = lane >> 4, lr = lane & 15;
  const int blk = blockIdx.x;
  const int xcd = blk & 7, slot = blk >> 3;
  const int bh = xcd * 4 + (slot >> 6);       // 4 bh per XCD
  const int r6 = slot & 63;
  const int qt = r6 >> 1, half = r6 & 1;
  const int q = qt * 64 + w * 16 + lr;
  const int kt0 = half * 16;                  // this block's 16 key-tiles

  const __hip_bfloat16* Qrow = Qs + ((size_t)bh * L + q) * 64;
  bf16x8 qf0 = *(const bf16x8*)(Qrow + g * 8);
  bf16x8 qf1 = *(const bf16x8*)(Qrow + 32 + g * 8);

  // Loop-invariant LDS addressing. Read addr(row=mf*16+lr, half ds/ks) =
  //   row*128 + ((ds*64 + g*16) ^ ((lr&7)<<4)); decomposed to 2 bases + imm.
  const int mask = (lr & 7) << 4;
  const int kb0 = lr * 128 + ((g * 16) ^ (mask & 0x30)) + (mask & 0x40);
  const int kb1 = kb0 ^ 64;
  // P-write (row = w*16+lr): w*2048 + lr*128 + ((mf*32 + g*8) ^ mask)
  const int pw0 = w * 2048 + lr * 128 + ((g * 8) ^ (mask & 0x10));
  const int q60 = mask & 0x60;

  // Staging source cursors (dest LDS offsets fixed; source pre-swizzled).
  const int c0 = tid * 16, c1 = c0 + 4096;
  const int osA = c0 ^ (((c0 >> 7) & 7) << 4);
  const int osB = c1 ^ (((c1 >> 7) & 7) << 4);
  const char* KsrcA = (const char*)(Ks + (size_t)bh * L * 64) + (size_t)kt0 * 8192 + osA;
  const char* KsrcB = (const char*)(Ks + (size_t)bh * L * 64) + (size_t)kt0 * 8192 + osB;
  const char* Vg = (const char*)(Vt + (size_t)bh * 64 * L) + (size_t)kt0 * 128;
  const char* VsrcA = Vg + (size_t)(osA >> 7) * (L * 2) + (osA & 127);
  const char* VsrcB = Vg + (size_t)(osB >> 7) * (L * 2) + (osB & 127);

  f32x4 oacc[4] = {};
  float mrun = -1e30f, lpart = 0.0f;

  for (int kt = 0; kt < 16; ++kt) {
    gl2lds16(KsrcA, (char*)Kt + c0);
    gl2lds16(KsrcB, (char*)Kt + c1);
    gl2lds16(VsrcA, (char*)Vts + c0);
    gl2lds16(VsrcB, (char*)Vts + c1);
    KsrcA += 8192; KsrcB += 8192; VsrcA += 128; VsrcB += 128;
    asm volatile("s_waitcnt vmcnt(0)" ::: "memory");
    asm volatile("s_barrier" ::: "memory");

    // QK^T (swapped): sacc[mf] = S^T[k-rows mf*16+4g+r][q=lr], log2 units
    f32x4 sacc[4] = {};
#pragma unroll
    for (int mf = 0; mf < 4; ++mf) {
      bf16x8 a0 = *(const bf16x8*)((const char*)Kt + kb0 + mf * 2048);
      bf16x8 a1 = *(const bf16x8*)((const char*)Kt + kb1 + mf * 2048);
      sacc[mf] = __builtin_amdgcn_mfma_f32_16x16x32_bf16(a0, qf0, sacc[mf], 0, 0, 0);
      sacc[mf] = __builtin_amdgcn_mfma_f32_16x16x32_bf16(a1, qf1, sacc[mf], 0, 0, 0);
    }
    asm volatile("s_waitcnt lgkmcnt(0)" ::: "memory");
    asm volatile("s_barrier" ::: "memory");  // all QK reads done; Kt -> P buffer

    // Online softmax (log2 units); defer-max rescale.
    float t0 = fmaxf(fmaxf(sacc[0][0], sacc[0][1]), fmaxf(sacc[0][2], sacc[0][3]));
    float t1 = fmaxf(fmaxf(sacc[1][0], sacc[1][1]), fmaxf(sacc[1][2], sacc[1][3]));
    float t2 = fmaxf(fmaxf(sacc[2][0], sacc[2][1]), fmaxf(sacc[2][2], sacc[2][3]));
    float t3 = fmaxf(fmaxf(sacc[3][0], sacc[3][1]), fmaxf(sacc[3][2], sacc[3][3]));
    float tmax = fmaxf(fmaxf(t0, t1), fmaxf(t2, t3));
    tmax = fmaxf(tmax, __shfl_xor(tmax, 16));
    tmax = fmaxf(tmax, __shfl_xor(tmax, 32));
    if (__any(tmax > mrun + 8.0f)) {
      float mnew = fmaxf(mrun, tmax);
      float al = __builtin_amdgcn_exp2f(mrun - mnew);
      mrun = mnew;
      lpart *= al;
#pragma unroll
      for (int d = 0; d < 4; ++d) oacc[d] = oacc[d] * al;
    }
#pragma unroll
    for (int mf = 0; mf < 4; ++mf) {
      float p0 = __builtin_amdgcn_exp2f(sacc[mf][0] - mrun);
      float p1 = __builtin_amdgcn_exp2f(sacc[mf][1] - mrun);
      float p2 = __builtin_amdgcn_exp2f(sacc[mf][2] - mrun);
      float p3 = __builtin_amdgcn_exp2f(sacc[mf][3] - mrun);
      lpart += (p0 + p1) + (p2 + p3);
      bf16x4v pk = { (__bf16)p0, (__bf16)p1, (__bf16)p2, (__bf16)p3 };
      *(bf16x4v*)((char*)Kt + (pw0 + (q60 ^ (mf * 32)))) = pk;
    }

    // PV: O^T = mfma(A=Vt, B=P); P read back from the Kt alias.
#pragma unroll
    for (int ks = 0; ks < 2; ++ks) {
      const int kb = ks ? kb1 : kb0;
      bf16x8 pf = *(const bf16x8*)((const char*)Kt + w * 2048 + kb);
#pragma unroll
      for (int df = 0; df < 4; ++df) {
        bf16x8 a = *(const bf16x8*)((const char*)Vts + kb + df * 2048);
        oacc[df] = __builtin_amdgcn_mfma_f32_16x16x32_bf16(a, pf, oacc[df], 0, 0, 0);
      }
    }
    asm volatile("s_waitcnt lgkmcnt(0)" ::: "memory");
    asm volatile("s_barrier" ::: "memory");  // reads done before next stage
  }

  lpart += __shfl_xor(lpart, 16);
  lpart += __shfl_xor(lpart, 32);

  const size_t rowi = ((size_t)bh * L + q) * 2 + half;
  float* Od = Opart + rowi * 64;
#pragma unroll
  for (int df = 0; df < 4; ++df)
    *(f32x4*)(Od + df * 16 + g * 4) = oacc[df];
  if (g == 0) {
    float2 ml; ml.x = mrun; ml.y = lpart;
    Ml[rowi] = ml;
  }
}

// ---------------- Split-K combine: Ob[b][l][h*64+d] = sum(Opart)/l ----------
__global__ __launch_bounds__(256) void attn_reduce(
    const float* __restrict__ Opart, const float2* __restrict__ Ml,
    unsigned short* __restrict__ Ob) {
  int t = blockIdx.x * 256 + threadIdx.x;
  int d = t & 63;
  int r = t >> 6;  // 0..65535 = bh*2048 + q
  float2 a = Ml[2 * r], b = Ml[2 * r + 1];
  float m = fmaxf(a.x, b.x);
  float w0 = __builtin_amdgcn_exp2f(a.x - m);
  float w1 = __builtin_amdgcn_exp2f(b.x - m);
  float l = a.y * w0 + b.y * w1;
  float o = Opart[(size_t)(2 * r) * 64 + d] * w0 + Opart[(size_t)(2 * r + 1) * 64 + d] * w1;
  float out = o / l;
  int bh = r >> 11, qq = r & 2047;
  Ob[(((size_t)(bh >> 4) * 2048 + qq)) * 1024 + (bh & 15) * 64 + d] = f2bf(out);
}

// ---------------- launch ----------------
extern "C" void kernel_launch(void* const* d_in, const int* in_sizes, int n_in,
                              void* d_out, int out_size, void* d_ws, size_t ws_size,
                              hipStream_t stream) {
  (void)in_sizes; (void)n_in; (void)out_size; (void)ws_size;
  const float* x    = (const float*)d_in[0];   // [2,2048,1024]
  const float* wqkv = (const float*)d_in[1];   // [3072,1024]
  const float* wout = (const float*)d_in[2];   // [1024,1024]

  char* ws = (char*)d_ws;
  // Workspace (59MB):
  //  [0..2M)   wob          (alive until gemm2)
  //  [2..10M)  Qsb, later Ob (Qsb dead after attn; Ob written by reduce)
  //  [10..18M) Ksb
  //  [18..26M) Vtb
  //  [26..50M) qkvb         (dead after rope) -- overlapped by Opart
  //  [26..58M) Opart (f32)  (written by attn, after qkvb/xb dead)
  //  [50..58M) xb           (dead after gemm1)
  //  [58..64M) wqb          (dead after gemm1) -- overlapped by Ml [58..59M)
  auto* wob   = (__hip_bfloat16*)(ws + ((size_t)0u  << 20));
  auto* Qsb   = (__hip_bfloat16*)(ws + ((size_t)2u  << 20));
  auto* Ob    = (__hip_bfloat16*)(ws + ((size_t)2u  << 20));
  auto* Ksb   = (__hip_bfloat16*)(ws + ((size_t)10u << 20));
  auto* Vtb   = (__hip_bfloat16*)(ws + ((size_t)18u << 20));
  auto* qkvb  = (__hip_bfloat16*)(ws + ((size_t)26u << 20));
  auto* Opart = (float*)         (ws + ((size_t)26u << 20));
  auto* xb    = (__hip_bfloat16*)(ws + ((size_t)50u << 20));
  auto* wqb   = (__hip_bfloat16*)(ws + ((size_t)58u << 20));
  auto* Mlp   = (float2*)        (ws + ((size_t)58u << 20));

  cvt_all<<<8192, 256, 0, stream>>>((const float4*)x, (const float4*)wqkv,
                                    (const float4*)wout,
                                    (ushort4*)xb, (ushort4*)wqb, (ushort4*)wob);
  gemm_bt<1><<<dim3(24, 32), 256, 0, stream>>>(xb, wqb, (void*)qkvb, 4096, 3072, 1024);
  rope_scatter<<<1024, 256, 0, stream>>>(qkvb, Qsb, Ksb, Vtb);
  attn_fwd<<<2048, 256, 0, stream>>>(Qsb, Ksb, Vtb, Opart, Mlp);
  attn_reduce<<<16384, 256, 0, stream>>>(Opart, Mlp, (unsigned short*)Ob);
  gemm_bt<0><<<dim3(8, 32), 256, 0, stream>>>(Ob, wob, d_out, 4096, 1024, 1024);
}

// Round 4
// 147.023 us; speedup vs baseline: 1.1462x; 1.0950x over previous
//
#include <hip/hip_runtime.h>
#include <hip/hip_bf16.h>
#include <stdint.h>

// Problem constants: B=2, L=2048, D=1024, H=16, hd=64, scale=1/8 (log2e-folded).

typedef __bf16 bf16x8 __attribute__((ext_vector_type(8)));
typedef __bf16 bf16x4v __attribute__((ext_vector_type(4)));
typedef float f32x4 __attribute__((ext_vector_type(4)));

__device__ __forceinline__ unsigned short f2bf(float f) {
  union { float f; unsigned int u; } v; v.f = f;
  unsigned int r = v.u + 0x7FFFu + ((v.u >> 16) & 1u);  // RNE
  return (unsigned short)(r >> 16);
}
__device__ __forceinline__ float b2f(unsigned short u) {
  union { unsigned int u; float f; } v; v.u = ((unsigned int)u) << 16;
  return v.f;
}

__device__ __forceinline__ void gl2lds16(const void* gptr, void* lptr) {
  __builtin_amdgcn_global_load_lds(
      (const __attribute__((address_space(1))) unsigned int*)gptr,
      (__attribute__((address_space(3))) unsigned int*)lptr, 16, 0, 0);
}

// ---------------- fp32 -> bf16 conversion (x | W_qkv | W_out) ----------------
__global__ void cvt_all(const float4* __restrict__ x,
                        const float4* __restrict__ wq,
                        const float4* __restrict__ wo,
                        ushort4* __restrict__ xb,
                        ushort4* __restrict__ wqb,
                        ushort4* __restrict__ wob) {
  int i = blockIdx.x * 256 + threadIdx.x;  // 0..2097151
  float4 v; ushort4* dst; int j;
  if (i < 1048576)      { v = x[i];            dst = xb;  j = i; }
  else if (i < 1835008) { v = wq[i - 1048576]; dst = wqb; j = i - 1048576; }
  else                  { v = wo[i - 1835008]; dst = wob; j = i - 1835008; }
  ushort4 o;
  o.x = f2bf(v.x); o.y = f2bf(v.y); o.z = f2bf(v.z); o.w = f2bf(v.w);
  dst[j] = o;
}

// ---------------- GEMM: C[M,N] = A[M,K] * B[N,K]^T (both K-contiguous) ------
template<int OUT_BF16>
__global__ __launch_bounds__(256) void gemm_bt(
    const __hip_bfloat16* __restrict__ A,
    const __hip_bfloat16* __restrict__ B,
    void* __restrict__ C, int M, int N, int K) {
  __shared__ __align__(16) __hip_bfloat16 As[128 * 32];
  __shared__ __align__(16) __hip_bfloat16 Bs[128 * 32];
  const int tid = threadIdx.x;
  const int lane = tid & 63;
  const int wave = tid >> 6;
  const int wm = (wave >> 1) * 64, wn = (wave & 1) * 64;
  const int g = lane >> 4, lr = lane & 15;
  const int m0 = blockIdx.y * 128, n0 = blockIdx.x * 128;
  f32x4 acc[4][4] = {};

  const char* Ag = (const char*)(A + (size_t)m0 * K);
  const char* Bg = (const char*)(B + (size_t)n0 * K);
  const size_t ldb = (size_t)K * 2;

  for (int kt = 0; kt < K; kt += 32) {
    const char* Ak = Ag + (size_t)kt * 2;
    const char* Bk = Bg + (size_t)kt * 2;
#pragma unroll
    for (int j = 0; j < 2; ++j) {
      int c = tid + j * 256;
      int row = c >> 2;
      int colb = (c & 3) * 16;
      gl2lds16(Ak + (size_t)row * ldb + colb, (char*)As + c * 16);
      gl2lds16(Bk + (size_t)row * ldb + colb, (char*)Bs + c * 16);
    }
    asm volatile("s_waitcnt vmcnt(0)" ::: "memory");
    __syncthreads();
    bf16x8 af[4], bfr[4];
#pragma unroll
    for (int i = 0; i < 4; ++i)
      af[i] = *(const bf16x8*)((const char*)As + (size_t)(wm + i * 16 + lr) * 64 + g * 16);
#pragma unroll
    for (int i = 0; i < 4; ++i)
      bfr[i] = *(const bf16x8*)((const char*)Bs + (size_t)(wn + i * 16 + lr) * 64 + g * 16);
#pragma unroll
    for (int i = 0; i < 4; ++i)
#pragma unroll
      for (int j = 0; j < 4; ++j)
        acc[i][j] = __builtin_amdgcn_mfma_f32_16x16x32_bf16(af[i], bfr[j], acc[i][j], 0, 0, 0);
    __syncthreads();
  }

#pragma unroll
  for (int i = 0; i < 4; ++i) {
#pragma unroll
    for (int j = 0; j < 4; ++j) {
      int n = n0 + wn + j * 16 + lr;
#pragma unroll
      for (int r = 0; r < 4; ++r) {
        int m = m0 + wm + i * 16 + g * 4 + r;
        float v = acc[i][j][r];
        if (OUT_BF16) {
          ((unsigned short*)C)[(size_t)m * N + n] = f2bf(v);
        } else {
          ((float*)C)[(size_t)m * N + n] = v;
        }
      }
    }
  }
}

// ---------------- RoPE + scatter to per-head Q,K,V(transposed) --------------
__global__ void rope_scatter(const __hip_bfloat16* __restrict__ qkv,
                             __hip_bfloat16* __restrict__ Qs,
                             __hip_bfloat16* __restrict__ Ks,
                             __hip_bfloat16* __restrict__ Vt) {
  const int t = blockIdx.x * 256 + threadIdx.x;  // 262144 total
  const int i = t & 31;
  const int lc = (t >> 5) & 255;
  const int h = (t >> 13) & 15;
  const int b = t >> 17;
  const float inv_freq = powf(10000.0f, -(float)i * (1.0f / 32.0f));
  const float QSCALE = 0.125f * 1.44269504088896f;  // scale * log2(e)
  const unsigned short* qk = (const unsigned short*)qkv;
  unsigned short v0[8], v1[8];
#pragma unroll
  for (int j = 0; j < 8; ++j) {
    const int l = lc * 8 + j;
    const size_t row = ((size_t)(b * 2048 + l)) * 3072;
    float s, c;
    sincosf((float)l * inv_freq, &s, &c);
    ushort2 qp = *(const ushort2*)(qk + row + h * 64 + 2 * i);
    ushort2 kp = *(const ushort2*)(qk + row + 1024 + h * 64 + 2 * i);
    ushort2 vp = *(const ushort2*)(qk + row + 2048 + h * 64 + 2 * i);
    float x1 = b2f(qp.x), x2 = b2f(qp.y);
    float y1 = b2f(kp.x), y2 = b2f(kp.y);
    size_t oidx = (((size_t)(b * 16 + h)) * 2048 + l) * 64 + 2 * i;
    ushort2 qo, ko;
    qo.x = f2bf((x1 * c - x2 * s) * QSCALE);
    qo.y = f2bf((x1 * s + x2 * c) * QSCALE);
    ko.x = f2bf(y1 * c - y2 * s);
    ko.y = f2bf(y1 * s + y2 * c);
    *(ushort2*)((unsigned short*)Qs + oidx) = qo;
    *(ushort2*)((unsigned short*)Ks + oidx) = ko;
    v0[j] = vp.x; v1[j] = vp.y;
  }
  unsigned short* Vtu = (unsigned short*)Vt;
  const size_t vrow0 = (((size_t)(b * 16 + h)) * 64 + 2 * i) * 2048 + lc * 8;
  const size_t vrow1 = vrow0 + 2048;
  *(ushort4*)(Vtu + vrow0)     = make_ushort4(v0[0], v0[1], v0[2], v0[3]);
  *(ushort4*)(Vtu + vrow0 + 4) = make_ushort4(v0[4], v0[5], v0[6], v0[7]);
  *(ushort4*)(Vtu + vrow1)     = make_ushort4(v1[0], v1[1], v1[2], v1[3]);
  *(ushort4*)(Vtu + vrow1 + 4) = make_ushort4(v1[4], v1[5], v1[6], v1[7]);
}

// ---------------- Flash attention, split-K=2, 2 q-groups/wave ---------------
// Grid: 512 blocks = (bh 0..31) x (qtile 0..7) x (half 0..1), XCD-swizzled.
// 8 waves x 32 q-rows (2 q-groups of 16). A-fragment (K/V) LDS reads are
// shared across both q-groups -> ~halved LDS bytes per q. K/V double-buffered
// (counted vmcnt, 2 barriers/iter); P in dedicated per-wave slabs (wave-local,
// no barrier). LDS = 16K K + 16K V + 32K P = 64KB exactly -> 2 blocks/CU.
__global__ __launch_bounds__(512, 4) void attn_fwd(
    const __hip_bfloat16* __restrict__ Qs,
    const __hip_bfloat16* __restrict__ Ks,
    const __hip_bfloat16* __restrict__ Vt,
    float* __restrict__ Opart,
    float2* __restrict__ Ml) {
  constexpr int L = 2048;
  extern __shared__ __align__(16) char lds[];  // [0,16K) Kt x2, [16K,32K) Vt x2, [32K,64K) P
  const int tid = threadIdx.x, lane = tid & 63, w = tid >> 6;
  const int g = lane >> 4, lr = lane & 15;
  const int blk = blockIdx.x;
  const int xcd = blk & 7, slot = blk >> 3;   // 64 slots per XCD
  const int bh = xcd * 4 + (slot >> 4);       // 4 bh per XCD
  const int rem = slot & 15;
  const int qt = rem >> 1, half = rem & 1;
  const int q0 = qt * 256 + w * 32 + lr;      // q-group 0 row; qg1 = q0+16
  const int kt0 = half * 16;                  // this block's 16 key-tiles

  const __hip_bfloat16* Qr = Qs + ((size_t)bh * L + q0) * 64;
  bf16x8 qf[2][2];
  qf[0][0] = *(const bf16x8*)(Qr + g * 8);
  qf[0][1] = *(const bf16x8*)(Qr + 32 + g * 8);
  qf[1][0] = *(const bf16x8*)(Qr + 16 * 64 + g * 8);
  qf[1][1] = *(const bf16x8*)(Qr + 16 * 64 + 32 + g * 8);

  // LDS read addressing (XOR-swizzled rows of 128B):
  //   frag(row=mf*16+lr, half ds) at row*128 + ((ds*64 + g*16) ^ ((lr&7)<<4))
  const int xmask = (lr & 7) << 4;
  const int loff0 = ((g * 16) ^ (xmask & 0x30)) + (xmask & 0x40);
  const int loff1 = loff0 ^ 64;
  const int kb0 = lr * 128 + loff0;
  const int kb1 = lr * 128 + loff1;
  // P slab: [wave][qg][16 q-rows][128B], same row-swizzle.
  char* Pme = lds + 32768 + w * 4096 + lr * 128;
  const int pwoff = (g * 8) ^ (xmask & 0x10);
  const int pm = xmask & 0x60;

  // Staging: one 16B K-chunk + one 16B V-chunk per thread per tile.
  const int c0 = tid * 16;
  const int os = c0 ^ (((c0 >> 7) & 7) << 4);  // involution
  const char* Ksrc = (const char*)(Ks + (size_t)bh * L * 64) + (size_t)kt0 * 8192 + os;
  const char* Vsrc = (const char*)(Vt + (size_t)bh * 64 * L) +
                     (size_t)(os >> 7) * (L * 2) + kt0 * 128 + (os & 127);

  auto stage = [&](int bo) {
    gl2lds16(Ksrc, lds + bo + c0);
    gl2lds16(Vsrc, lds + 16384 + bo + c0);
    Ksrc += 8192; Vsrc += 128;
  };

  f32x4 oacc[2][4] = {};
  float mrun[2] = {-1e30f, -1e30f}, lpart[2] = {0.0f, 0.0f};

  stage(0);  // prologue: tile kt0 into buffer 0

  for (int kt = 0; kt < 16; ++kt) {
    const int bo = (kt & 1) * 8192;
    if (kt + 1 < 16) {
      stage(bo ^ 8192);
      asm volatile("s_waitcnt vmcnt(2)" ::: "memory");  // cur tile's 2 loads done
    } else {
      asm volatile("s_waitcnt vmcnt(0)" ::: "memory");
    }
    asm volatile("s_barrier" ::: "memory");

    const char* Kc = lds + bo;
    const char* Vc = lds + 16384 + bo;

    // QK^T (swapped): sacc[qg][mf] = S^T[k=mf*16+4g+r][q], log2 units.
    f32x4 sacc[2][4] = {};
#pragma unroll
    for (int mf = 0; mf < 4; ++mf) {
      bf16x8 a0 = *(const bf16x8*)(Kc + kb0 + mf * 2048);
      bf16x8 a1 = *(const bf16x8*)(Kc + kb1 + mf * 2048);
      sacc[0][mf] = __builtin_amdgcn_mfma_f32_16x16x32_bf16(a0, qf[0][0], sacc[0][mf], 0, 0, 0);
      sacc[0][mf] = __builtin_amdgcn_mfma_f32_16x16x32_bf16(a1, qf[0][1], sacc[0][mf], 0, 0, 0);
      sacc[1][mf] = __builtin_amdgcn_mfma_f32_16x16x32_bf16(a0, qf[1][0], sacc[1][mf], 0, 0, 0);
      sacc[1][mf] = __builtin_amdgcn_mfma_f32_16x16x32_bf16(a1, qf[1][1], sacc[1][mf], 0, 0, 0);
    }

    // Online softmax per q-group (log2 units); defer-max rescale.
#pragma unroll
    for (int qg = 0; qg < 2; ++qg) {
      float t0 = fmaxf(fmaxf(sacc[qg][0][0], sacc[qg][0][1]), fmaxf(sacc[qg][0][2], sacc[qg][0][3]));
      float t1 = fmaxf(fmaxf(sacc[qg][1][0], sacc[qg][1][1]), fmaxf(sacc[qg][1][2], sacc[qg][1][3]));
      float t2 = fmaxf(fmaxf(sacc[qg][2][0], sacc[qg][2][1]), fmaxf(sacc[qg][2][2], sacc[qg][2][3]));
      float t3 = fmaxf(fmaxf(sacc[qg][3][0], sacc[qg][3][1]), fmaxf(sacc[qg][3][2], sacc[qg][3][3]));
      float tmax = fmaxf(fmaxf(t0, t1), fmaxf(t2, t3));
      tmax = fmaxf(tmax, __shfl_xor(tmax, 16));
      tmax = fmaxf(tmax, __shfl_xor(tmax, 32));
      if (__any(tmax > mrun[qg] + 8.0f)) {
        float mnew = fmaxf(mrun[qg], tmax);
        float al = __builtin_amdgcn_exp2f(mrun[qg] - mnew);
        mrun[qg] = mnew;
        lpart[qg] *= al;
#pragma unroll
        for (int d = 0; d < 4; ++d) oacc[qg][d] = oacc[qg][d] * al;
      }
#pragma unroll
      for (int mf = 0; mf < 4; ++mf) {
        float p0 = __builtin_amdgcn_exp2f(sacc[qg][mf][0] - mrun[qg]);
        float p1 = __builtin_amdgcn_exp2f(sacc[qg][mf][1] - mrun[qg]);
        float p2 = __builtin_amdgcn_exp2f(sacc[qg][mf][2] - mrun[qg]);
        float p3 = __builtin_amdgcn_exp2f(sacc[qg][mf][3] - mrun[qg]);
        lpart[qg] += (p0 + p1) + (p2 + p3);
        bf16x4v pk = { (__bf16)p0, (__bf16)p1, (__bf16)p2, (__bf16)p3 };
        *(bf16x4v*)(Pme + qg * 2048 + pwoff + ((mf * 32) ^ pm)) = pk;
      }
    }

    // PV interleaved over q-groups: one V-frag read feeds both oacc sets.
#pragma unroll
    for (int ks = 0; ks < 2; ++ks) {
      const int lo = ks ? loff1 : loff0;
      bf16x8 pf0 = *(const bf16x8*)(Pme + lo);
      bf16x8 pf1 = *(const bf16x8*)(Pme + 2048 + lo);
#pragma unroll
      for (int df = 0; df < 4; ++df) {
        bf16x8 a = *(const bf16x8*)(Vc + (ks ? kb1 : kb0) + df * 2048);
        oacc[0][df] = __builtin_amdgcn_mfma_f32_16x16x32_bf16(a, pf0, oacc[0][df], 0, 0, 0);
        oacc[1][df] = __builtin_amdgcn_mfma_f32_16x16x32_bf16(a, pf1, oacc[1][df], 0, 0, 0);
      }
    }
    asm volatile("s_waitcnt lgkmcnt(0)" ::: "memory");
    __builtin_amdgcn_sched_barrier(0);
    asm volatile("s_barrier" ::: "memory");  // cur buffers free for next stage
  }

#pragma unroll
  for (int qg = 0; qg < 2; ++qg) {
    float lsum = lpart[qg];
    lsum += __shfl_xor(lsum, 16);
    lsum += __shfl_xor(lsum, 32);
    const size_t rowi = ((size_t)bh * L + q0 + qg * 16) * 2 + half;
    float* Od = Opart + rowi * 64;
#pragma unroll
    for (int df = 0; df < 4; ++df)
      *(f32x4*)(Od + df * 16 + g * 4) = oacc[qg][df];
    if (g == 0) {
      float2 ml; ml.x = mrun[qg]; ml.y = lsum;
      Ml[rowi] = ml;
    }
  }
}

// ---------------- Split-K combine: Ob[b][l][h*64+d] = sum(Opart)/l ----------
__global__ __launch_bounds__(256) void attn_reduce(
    const float* __restrict__ Opart, const float2* __restrict__ Ml,
    unsigned short* __restrict__ Ob) {
  int t = blockIdx.x * 256 + threadIdx.x;
  int d = t & 63;
  int r = t >> 6;  // 0..65535 = bh*2048 + q
  float2 a = Ml[2 * r], b = Ml[2 * r + 1];
  float m = fmaxf(a.x, b.x);
  float w0 = __builtin_amdgcn_exp2f(a.x - m);
  float w1 = __builtin_amdgcn_exp2f(b.x - m);
  float l = a.y * w0 + b.y * w1;
  float o = Opart[(size_t)(2 * r) * 64 + d] * w0 + Opart[(size_t)(2 * r + 1) * 64 + d] * w1;
  float out = o / l;
  int bh = r >> 11, qq = r & 2047;
  Ob[(((size_t)(bh >> 4) * 2048 + qq)) * 1024 + (bh & 15) * 64 + d] = f2bf(out);
}

// ---------------- launch ----------------
extern "C" void kernel_launch(void* const* d_in, const int* in_sizes, int n_in,
                              void* d_out, int out_size, void* d_ws, size_t ws_size,
                              hipStream_t stream) {
  (void)in_sizes; (void)n_in; (void)out_size; (void)ws_size;
  const float* x    = (const float*)d_in[0];   // [2,2048,1024]
  const float* wqkv = (const float*)d_in[1];   // [3072,1024]
  const float* wout = (const float*)d_in[2];   // [1024,1024]

  char* ws = (char*)d_ws;
  // Workspace (59MB):
  //  [0..2M)   wob          (alive until gemm2)
  //  [2..10M)  Qsb, later Ob (Qsb dead after attn; Ob written by reduce)
  //  [10..18M) Ksb
  //  [18..26M) Vtb
  //  [26..50M) qkvb         (dead after rope) -- overlapped by Opart
  //  [26..58M) Opart (f32)
  //  [50..58M) xb           (dead after gemm1)
  //  [58..64M) wqb          (dead after gemm1) -- overlapped by Ml [58..59M)
  auto* wob   = (__hip_bfloat16*)(ws + ((size_t)0u  << 20));
  auto* Qsb   = (__hip_bfloat16*)(ws + ((size_t)2u  << 20));
  auto* Ob    = (__hip_bfloat16*)(ws + ((size_t)2u  << 20));
  auto* Ksb   = (__hip_bfloat16*)(ws + ((size_t)10u << 20));
  auto* Vtb   = (__hip_bfloat16*)(ws + ((size_t)18u << 20));
  auto* qkvb  = (__hip_bfloat16*)(ws + ((size_t)26u << 20));
  auto* Opart = (float*)         (ws + ((size_t)26u << 20));
  auto* xb    = (__hip_bfloat16*)(ws + ((size_t)50u << 20));
  auto* wqb   = (__hip_bfloat16*)(ws + ((size_t)58u << 20));
  auto* Mlp   = (float2*)        (ws + ((size_t)58u << 20));

  cvt_all<<<8192, 256, 0, stream>>>((const float4*)x, (const float4*)wqkv,
                                    (const float4*)wout,
                                    (ushort4*)xb, (ushort4*)wqb, (ushort4*)wob);
  gemm_bt<1><<<dim3(24, 32), 256, 0, stream>>>(xb, wqb, (void*)qkvb, 4096, 3072, 1024);
  rope_scatter<<<1024, 256, 0, stream>>>(qkvb, Qsb, Ksb, Vtb);
  attn_fwd<<<512, 512, 65536, stream>>>(Qsb, Ksb, Vtb, Opart, Mlp);
  attn_reduce<<<16384, 256, 0, stream>>>(Opart, Mlp, (unsigned short*)Ob);
  gemm_bt<0><<<dim3(8, 32), 256, 0, stream>>>(Ob, wob, d_out, 4096, 1024, 1024);
}